// Round 10
// baseline (329.447 us; speedup 1.0000x reference)
//
#include <hip/hip_runtime.h>

#define NN 20000
#define EE 320000
#define BB 64
#define DD 256
#define DEPTH 3
#define NT (NN + BB)   // h rows + hs rows appended (NT = 20064 = 16*1254 = 48*418 = 8*2508)

typedef __attribute__((ext_vector_type(8))) short short8;
typedef __attribute__((ext_vector_type(4))) float floatx4;

// ---------------------------------------------------------------- bf16 split helpers
__device__ __forceinline__ short f2bf(float x) {
  union { float f; unsigned u; } v; v.f = x;
  unsigned r = v.u + 0x7fffu + ((v.u >> 16) & 1u);  // RNE
  return (short)(r >> 16);
}
__device__ __forceinline__ float bf2f(short s) {
  union { unsigned u; float f; } v; v.u = ((unsigned)(unsigned short)s) << 16;
  return v.f;
}

// ---------------------------------------------------------------- fragment-order split store
// A-fragment layout: Af[(((row>>4)*8 + kc)*2 + plane)*512 + (kg*16 + (row&15))*8 + kel]
// (shorts; plane 0 = hi, 1 = lo; kc = k>>5, kg = (k>>3)&3, kel = k&7). A wave's 16x32
// fragment is ONE contiguous coalesced 1KB load in kUpdM.
__device__ __forceinline__ void storeFragRow8(short* __restrict__ P, int row, int c0,
                                              const float* a) {
  short8 H, L;
  #pragma unroll
  for (int k = 0; k < 8; k++) {
    short hh = f2bf(a[k]);
    H[k] = hh;
    L[k] = f2bf(a[k] - bf2f(hh));
  }
  int kc = c0 >> 5, kg = (c0 >> 3) & 3;
  size_t u = ((size_t)((row >> 4) * 8 + kc) * 2) * 512 + (size_t)(kg * 16 + (row & 15)) * 8;
  *(short8*)(P + u) = H;
  *(short8*)(P + u + 512) = L;
}

// ---------------------------------------------------------------- reductions
__device__ __forceinline__ float blockSum256(float v, float* tmp) {
  #pragma unroll
  for (int o = 32; o > 0; o >>= 1) v += __shfl_down(v, o, 64);
  if ((threadIdx.x & 63) == 0) tmp[threadIdx.x >> 6] = v;
  __syncthreads();
  float r = tmp[0] + tmp[1] + tmp[2] + tmp[3];
  __syncthreads();
  return r;
}

// ---------------------------------------------------------------- kPre: rank atomics + kM + encode
// round-27: batch-side GLOBAL atomics ELIMINATED. The old rs[j]=atomicAdd(&curb[j],..)
// put 80K returning atomics (1250 blocks x 64 batches) onto ONE 256B region -> one
// L2 channel's atomic unit serialized them. This was the only rank-phase component
// untouched by 4 null kPre experiments (r2/r5/r6/r9). Now: LDS-only local rank +
// per-block histogram bhist[bid][64] (coalesced store); kAux turns bhist into
// deterministic global bases. Node-side privatized curn8 atomics kept (r9).
#define NCB ((EE + 255) / 256)   // 1250
#define NBB ((NN + 255) / 256)   // 79 (blocks that contain nodes)
__global__ __launch_bounds__(256) void kPre(const float* __restrict__ X,
                                            const float* __restrict__ Xs,
                                            const float* __restrict__ W1,
                                            short* __restrict__ hg,
                                            short* __restrict__ Af,
                                            const int* __restrict__ dst,
                                            const int* __restrict__ bassign,
                                            int* curn8,
                                            int* __restrict__ bhist,
                                            int* __restrict__ rank,
                                            int* __restrict__ rankB,
                                            const float* __restrict__ W2,
                                            const float* __restrict__ W3,
                                            const float* __restrict__ linW,
                                            short* __restrict__ Bf) {
  __shared__ int hc[64];
  __shared__ __align__(16) short Hs[16][264];   // 264: stride 132 dwords %32 = 4 -> <=2-way
  __shared__ __align__(16) short Ls[16][264];
  float (*Wl)[DD] = (float(*)[DD])&Hs[0][0];    // M-phase overlay: 8KB <= Hs' 8.4KB
  int bid = blockIdx.x, j = threadIdx.x;
  if (bid < NCB) {
    if (j < 64) hc[j] = 0;
    __syncthreads();
    int t = bid * 256 + j;
    if (t < NN) rankB[t] = atomicAdd(&hc[bassign[t]], 1);     // LDS-only local rank
    if (t < EE) rank[t] = atomicAdd(&curn8[(bid & 7) * NN + dst[t]], 1);
    __syncthreads();
    if (bid < NBB && j < 64) bhist[bid * 64 + j] = hc[j];     // coalesced, non-atomic
  } else if (bid < NCB + 64) {
    // ---- M' rows rbase..rbase+7 (M2 = W2 @ linW_top for rows<256, else M3)
    int rbase = (bid - NCB) * 8;                 // 0..504
    bool second = rbase >= 256;
    const float* W = second ? W3 : W2;
    const float* L = linW + (second ? DD * DD : 0);
    int i0 = second ? (rbase - 256) : rbase;
    for (int q = j; q < 8 * DD; q += 256) Wl[q >> 8][q & 255] = W[(size_t)(i0 + (q >> 8)) * DD + (q & 255)];
    __syncthreads();
    float acc[8];
    #pragma unroll
    for (int r = 0; r < 8; r++) acc[r] = 0.f;
    #pragma unroll 4
    for (int k = 0; k < DD; k++) {
      float lv = L[(size_t)k * DD + j];
      #pragma unroll
      for (int r = 0; r < 8; r++) acc[r] = fmaf(Wl[r][k], lv, acc[r]);
    }
    #pragma unroll
    for (int r = 0; r < 8; r++) {
      int kk = rbase + r;                        // row index in B' (0..511)
      short hi = f2bf(acc[r]);
      short lo = f2bf(acc[r] - bf2f(hi));
      int kc = kk >> 5, kg = (kk >> 3) & 3, kel = kk & 7;
      int n16 = j >> 4, m16 = j & 15;
      size_t idx = ((size_t)(kc * 16 + n16) * 2) * 512 + (kg * 16 + m16) * 8 + kel;
      Bf[idx] = hi;
      Bf[idx + 512] = lo;
    }
  } else {
    // ---- encode: 16 rows per block, 16 threads/row x 16 cols/thread
    int rg = bid - NCB - 64;         // row-group 0..1253
    int rl = j >> 4;                 // row-in-group 0..15 (16 lanes each, shfl<16 safe)
    int ci = j & 15;
    int r = rg * 16 + rl;
    int c0 = ci * 16;
    const float* x = (r < NN) ? (X + (size_t)r * 2) : (Xs + (size_t)(r - NN) * 2);
    float x0 = x[0], x1 = x[1];
    float v[16];
    float ss = 0.f;
    #pragma unroll
    for (int q = 0; q < 4; q++) {
      float4 wa = *(const float4*)(W1 + c0 + q * 4);
      float4 wb = *(const float4*)(W1 + DD + c0 + q * 4);
      float a0 = fmaxf(fmaf(x0, wa.x, x1 * wb.x), 0.f);
      float a1 = fmaxf(fmaf(x0, wa.y, x1 * wb.y), 0.f);
      float a2 = fmaxf(fmaf(x0, wa.z, x1 * wb.z), 0.f);
      float a3 = fmaxf(fmaf(x0, wa.w, x1 * wb.w), 0.f);
      v[q * 4 + 0] = a0; v[q * 4 + 1] = a1; v[q * 4 + 2] = a2; v[q * 4 + 3] = a3;
      ss = fmaf(a0, a0, ss); ss = fmaf(a1, a1, ss);
      ss = fmaf(a2, a2, ss); ss = fmaf(a3, a3, ss);
    }
    #pragma unroll
    for (int o = 1; o < 16; o <<= 1) ss += __shfl_xor(ss, o, 64);
    float inv = 1.f / fmaxf(sqrtf(ss), 1e-12f);
    short8 H0, H1, L0, L1;
    #pragma unroll
    for (int k = 0; k < 8; k++) {
      float s0 = v[k] * inv;
      float s1 = v[8 + k] * inv;
      short h0 = f2bf(s0), h1 = f2bf(s1);
      H0[k] = h0; H1[k] = h1;
      L0[k] = f2bf(s0 - bf2f(h0)); L1[k] = f2bf(s1 - bf2f(h1));
    }
    *(short8*)(hg + (size_t)r * DD + c0)     = H0;
    *(short8*)(hg + (size_t)r * DD + c0 + 8) = H1;
    *(short8*)&Hs[rl][c0] = H0;  *(short8*)&Hs[rl][c0 + 8] = H1;
    *(short8*)&Ls[rl][c0] = L0;  *(short8*)&Ls[rl][c0 + 8] = L1;
    __syncthreads();
    // ---- coalesced fragment write: thread j covers fragment kc=j>>5, positions j&31, +32
    int kc = j >> 5, p0 = j & 31;
    #pragma unroll
    for (int half = 0; half < 2; half++) {
      int p = p0 + half * 32;
      int prow = p & 15, kg = p >> 4;
      size_t ub = ((size_t)(rg * 8 + kc) * 2) * 512 + (size_t)p * 8;
      *(short8*)(Af + ub)       = *(const short8*)&Hs[prow][kc * 32 + kg * 8];
      *(short8*)(Af + ub + 512) = *(const short8*)&Ls[prow][kc * 32 + kg * 8];
    }
  }
}

// ---------------------------------------------------------------- kAux: sum8 + batch-base scan
// round-27: replaces kSum8 (same launch count). Blocks [0,NBB): per-node 8-copy
// reduce (curn totals + pre8 copy-prefixes). Blocks [NBB,NBB+64): one per batch b,
// wave-0 shfl-scan over bhist[*][b] -> gpre[blk][b] (deterministic global base)
// and curb[b] totals (feeds kScan's offb scan; no global atomics anywhere).
__global__ __launch_bounds__(256) void kAux(const int* __restrict__ curn8,
                                            int* __restrict__ curn,
                                            int* __restrict__ pre8,
                                            const int* __restrict__ bhist,
                                            int* __restrict__ gpre,
                                            int* __restrict__ curb) {
  int bid = blockIdx.x;
  if (bid < NBB) {
    int n = bid * 256 + threadIdx.x;
    if (n < NN) {
      int run = 0;
      #pragma unroll
      for (int c = 0; c < 8; c++) {
        pre8[c * NN + n] = run;
        run += curn8[c * NN + n];
      }
      curn[n] = run;
    }
  } else {
    int b = bid - NBB;               // batch 0..63
    int lane = threadIdx.x;
    if (lane < 64) {
      int run = 0;
      for (int base = 0; base < NBB; base += 64) {
        int idx = base + lane;
        int v = (idx < NBB) ? bhist[idx * 64 + b] : 0;
        int incl = v;
        #pragma unroll
        for (int o = 1; o < 64; o <<= 1) {
          int x = __shfl_up(incl, o, 64);
          if (lane >= o) incl += x;
        }
        if (idx < NBB) gpre[idx * 64 + b] = run + (incl - v);
        run += __shfl(incl, 63, 64);
      }
      if (lane == 0) curb[b] = run;
    }
  }
}

// ---------------------------------------------------------------- CSR scan (single-copy form)
__global__ __launch_bounds__(1024) void kScan(const int* __restrict__ curn,
                                              int* offn,
                                              const int* __restrict__ curb,
                                              int* offb) {
  __shared__ int sums[1024];
  int t = threadIdx.x;
  const int CH = 20;  // 1024*20 = 20480 >= NN
  int base = t * CH;
  int local[CH];
  int s = 0;
  #pragma unroll
  for (int i = 0; i < CH; i++) {
    int idx = base + i;
    int v = (idx < NN) ? curn[idx] : 0;
    local[i] = s;
    s += v;
  }
  sums[t] = s;
  __syncthreads();
  for (int o = 1; o < 1024; o <<= 1) {
    int x = (t >= o) ? sums[t - o] : 0;
    __syncthreads();
    sums[t] += x;
    __syncthreads();
  }
  int excl = sums[t] - s;
  #pragma unroll
  for (int i = 0; i < CH; i++) {
    int idx = base + i;
    if (idx < NN) offn[idx] = excl + local[i];
  }
  if (t == 1023) offn[NN] = sums[1023];
  // batch offsets: 64-lane shuffle scan (first wave)
  if (t < 64) {
    int v = curb[t];
    int incl = v;
    #pragma unroll
    for (int o = 1; o < 64; o <<= 1) {
      int x = __shfl_up(incl, o, 64);
      if (t >= o) incl += x;
    }
    offb[t] = incl - v;
    if (t == 63) offb[BB] = incl;
  }
}

// ---------------------------------------------------------------- kPlace: rank -> position, no atomics
// round-27: batch slot = offb[b] + gpre[t>>8][b] + rankB (deterministic block-major).
__global__ __launch_bounds__(256) void kPlace(const int* __restrict__ src,
                                              const int* __restrict__ dst,
                                              const float* __restrict__ w,
                                              const int* __restrict__ bassign,
                                              const int* __restrict__ offn,
                                              const int* __restrict__ pre8,
                                              const int* __restrict__ offb,
                                              const int* __restrict__ gpre,
                                              const int* __restrict__ rank,
                                              const int* __restrict__ rankB,
                                              long long* sedge, int* snode) {
  int t = blockIdx.x * 256 + threadIdx.x;
  if (t < EE) {
    unsigned long long e = (unsigned long long)(unsigned)src[t]
                         | ((unsigned long long)(unsigned)__float_as_int(w[t]) << 32);
    int c = (t >> 8) & 7;                      // kPre rank-block id & 7
    int d = dst[t];
    sedge[offn[d] + pre8[c * NN + d] + rank[t]] = (long long)e;
  }
  if (t < NN) {
    int b = bassign[t];
    snode[offb[b] + gpre[(t >> 8) * 64 + b] + rankB[t]] = t;
  }
}

// ---------------------------------------------------------------- aggregation (free-running waves)
// round-24: ONE FREE-RUNNING WAVE per (node, slice), zero LDS, zero __syncthreads.
// Declared at line-service floor (3 structures converge at ~38-40us).
__global__ __launch_bounds__(512) void kAgg(const short* __restrict__ hg,
                                            const int* __restrict__ offn,
                                            const long long* __restrict__ sedge,
                                            const int* __restrict__ offb,
                                            const int* __restrict__ snode,
                                            short* __restrict__ Avf) {
  int bid = blockIdx.x;
  int slice = bid & 3, group = bid >> 2;      // group 0..2507
  int t = threadIdx.x;
  int w = t >> 6, lane = t & 63;
  int eg = lane >> 3;          // edge group 0..7
  int pc = lane & 7;           // 16B piece 0..7
  int colB = slice * 64 + pc * 8;             // 8 bf16 cols per lane
  float acc[8];
  #pragma unroll
  for (int jj = 0; jj < 8; jj++) acc[jj] = 0.f;

  if (group < 8) {
    // ---- batch rows: row b0+w per wave, snode index list (weight 1)
    int row = group * 8 + w;                  // 0..63
    int s = offb[row], e = offb[row + 1];
    for (int i = s; i < e; i += 16) {
      int i0 = i + eg, i1 = i + 8 + eg;
      int n0 = snode[min(i0, e - 1)];
      int n1 = snode[min(i1, e - 1)];
      float w0 = (i0 < e) ? 1.f : 0.f;
      float w1 = (i1 < e) ? 1.f : 0.f;
      short8 a0 = *(const short8*)(hg + (size_t)n0 * DD + colB);
      short8 a1 = *(const short8*)(hg + (size_t)n1 * DD + colB);
      #pragma unroll
      for (int jj = 0; jj < 8; jj++)
        acc[jj] = fmaf(w1, bf2f(a1[jj]), fmaf(w0, bf2f(a0[jj]), acc[jj]));
    }
    #pragma unroll
    for (int o = 8; o < 64; o <<= 1)
      #pragma unroll
      for (int jj = 0; jj < 8; jj++) acc[jj] += __shfl_xor(acc[jj], o, 64);
    if (eg == 0) storeFragRow8(Avf, NN + row, colB, acc);
  } else {
    // ---- edge nodes: node first+w per wave, sedge packed (src | w<<32)
    int node = (group - 8) * 8 + w;
    int s = offn[node], e = offn[node + 1];
    for (int i = s; i < e; i += 16) {
      int i0 = i + eg, i1 = i + 8 + eg;
      long long e0v = sedge[min(i0, e - 1)];
      long long e1v = sedge[min(i1, e - 1)];
      float w0 = (i0 < e) ? __int_as_float((int)(e0v >> 32)) : 0.f;
      float w1 = (i1 < e) ? __int_as_float((int)(e1v >> 32)) : 0.f;
      unsigned r0 = (unsigned)(e0v & 0xffffffffLL);
      unsigned r1 = (unsigned)(e1v & 0xffffffffLL);
      short8 a0 = *(const short8*)(hg + (size_t)r0 * DD + colB);
      short8 a1 = *(const short8*)(hg + (size_t)r1 * DD + colB);
      #pragma unroll
      for (int jj = 0; jj < 8; jj++)
        acc[jj] = fmaf(w1, bf2f(a1[jj]), fmaf(w0, bf2f(a0[jj]), acc[jj]));
    }
    #pragma unroll
    for (int o = 8; o < 64; o <<= 1)
      #pragma unroll
      for (int jj = 0; jj < 8; jj++) acc[jj] += __shfl_xor(acc[jj], o, 64);
    if (eg == 0) storeFragRow8(Avf, node, colB, acc);
  }
}

// ---------------------------------------------------------------- MFMA dual-GEMM + fused l2norm
// TRU=48 (r5 best). DMA double-buffered per-wave staging, barrier-free main loop.
#define TRU 48
__global__ __launch_bounds__(512) void kUpdM(short* __restrict__ Af,
                                             const short* __restrict__ Avf,
                                             const short* __restrict__ Bf,
                                             const float* __restrict__ lb,
                                             short* __restrict__ hg) {
  __shared__ __align__(16) short Bst[8][2][4][512];   // [wave][buf][ct*2+plane][512] = 64KB
  __shared__ float ssq[8][TRU];
  float (*Ct)[260] = (float(*)[260]) & Bst[0][0][0][0];   // epilogue overlay (49.9KB)
  const int t = threadIdx.x;
  const int rb = blockIdx.x * TRU;
  const int wid = t >> 6;          // 0..7
  const int lane = t & 63;
  const int wc = wid * 32;         // wave col offset (8 waves cover 256 cols)
  const int m16 = lane & 15;
  const int kg = lane >> 4;        // 0..3
  const int r16b = blockIdx.x * 3; // first 16-row group

  floatx4 acc[3][2];
  #pragma unroll
  for (int ct = 0; ct < 2; ct++) {
    float b = lb[wc + ct * 16 + m16];
    #pragma unroll
    for (int rt = 0; rt < 3; rt++) acc[rt][ct] = (floatx4){b, b, b, b};
  }

  short8 aH[2][3], aL[2][3];       // [kc&1][rt] -- static indices after full unroll

  // prologue: stage kc=0, load A(0)
  #pragma unroll
  for (int f = 0; f < 4; f++) {
    const short* g = Bf + ((size_t)((0 * 16 + wid * 2) * 2 + f)) * 512 + lane * 8;
    __builtin_amdgcn_global_load_lds((const __attribute__((address_space(1))) unsigned int*)g,
                                     (__attribute__((address_space(3))) unsigned int*)&Bst[wid][0][f][0],
                                     16, 0, 0);
  }
  #pragma unroll
  for (int rt = 0; rt < 3; rt++) {
    const short* ap = Af + ((size_t)((r16b + rt) * 8 + 0) * 2) * 512 + lane * 8;
    aH[0][rt] = *(const short8*)ap;
    aL[0][rt] = *(const short8*)(ap + 512);
  }

  #pragma unroll
  for (int kc = 0; kc < 16; kc++) {
    const int buf = kc & 1;
    if (kc < 15) {
      #pragma unroll
      for (int f = 0; f < 4; f++) {
        const short* g = Bf + ((size_t)(((kc + 1) * 16 + wid * 2) * 2 + f)) * 512 + lane * 8;
        __builtin_amdgcn_global_load_lds((const __attribute__((address_space(1))) unsigned int*)g,
                                         (__attribute__((address_space(3))) unsigned int*)&Bst[wid][buf ^ 1][f][0],
                                         16, 0, 0);
      }
      asm volatile("s_waitcnt vmcnt(4)" ::: "memory");
    } else {
      asm volatile("s_waitcnt vmcnt(0)" ::: "memory");
    }
    __builtin_amdgcn_sched_barrier(0);
    if (kc < 15) {
      const short* Ab = ((kc + 1) < 8) ? Af : Avf;
      const int kcl = (kc + 1) & 7;
      #pragma unroll
      for (int rt = 0; rt < 3; rt++) {
        const short* ap = Ab + ((size_t)((r16b + rt) * 8 + kcl) * 2) * 512 + lane * 8;
        aH[(kc + 1) & 1][rt] = *(const short8*)ap;
        aL[(kc + 1) & 1][rt] = *(const short8*)(ap + 512);
      }
    }
    #pragma unroll
    for (int ct = 0; ct < 2; ct++) {
      short8 bh = *(const short8*)&Bst[wid][buf][ct * 2 + 0][lane * 8];
      short8 bl = *(const short8*)&Bst[wid][buf][ct * 2 + 1][lane * 8];
      #pragma unroll
      for (int rt = 0; rt < 3; rt++) {
        acc[rt][ct] = __builtin_amdgcn_mfma_f32_16x16x32_bf16(aH[buf][rt], bh, acc[rt][ct], 0, 0, 0);
        acc[rt][ct] = __builtin_amdgcn_mfma_f32_16x16x32_bf16(aH[buf][rt], bl, acc[rt][ct], 0, 0, 0);
        acc[rt][ct] = __builtin_amdgcn_mfma_f32_16x16x32_bf16(aL[buf][rt], bh, acc[rt][ct], 0, 0, 0);
      }
    }
  }

  // ---- epilogue: relu + row l2norm (C/D: col=lane&15, row=(lane>>4)*4+reg)
  float p[3][4];
  #pragma unroll
  for (int rt = 0; rt < 3; rt++)
    #pragma unroll
    for (int reg = 0; reg < 4; reg++) {
      float s = 0.f;
      #pragma unroll
      for (int ct = 0; ct < 2; ct++) {
        float x = fmaxf(acc[rt][ct][reg], 0.f);
        s = fmaf(x, x, s);
      }
      p[rt][reg] = s;
    }
  #pragma unroll
  for (int o = 1; o < 16; o <<= 1)
    #pragma unroll
    for (int rt = 0; rt < 3; rt++)
      #pragma unroll
      for (int reg = 0; reg < 4; reg++)
        p[rt][reg] += __shfl_xor(p[rt][reg], o, 64);
  if (m16 == 0) {
    #pragma unroll
    for (int rt = 0; rt < 3; rt++)
      #pragma unroll
      for (int reg = 0; reg < 4; reg++)
        ssq[wid][rt * 16 + kg * 4 + reg] = p[rt][reg];
  }
  __syncthreads();   // after this barrier all waves are past their last Bst read
  #pragma unroll
  for (int rt = 0; rt < 3; rt++) {
    #pragma unroll
    for (int reg = 0; reg < 4; reg++) {
      int row = rt * 16 + kg * 4 + reg;
      float ss = 0.f;
      #pragma unroll
      for (int ww = 0; ww < 8; ww++) ss += ssq[ww][row];
      float inv = 1.f / fmaxf(sqrtf(ss), 1e-12f);
      #pragma unroll
      for (int ct = 0; ct < 2; ct++) {
        int col = wc + ct * 16 + m16;
        Ct[row][col] = fmaxf(acc[rt][ct][reg], 0.f) * inv;
      }
    }
  }
  __syncthreads();
  // ---- fragment-order split write-back (in-place Af) + bf16 hg, 16B stores
  const int fl = lane;                 // lane-in-fragment
  const int fk = wid;                  // kc 0..7
  #pragma unroll
  for (int r16o = 0; r16o < 3; ++r16o) {
    int row = r16o * 16 + (fl & 15);
    int k0 = fk * 32 + (fl >> 4) * 8;
    float4 xa = *(const float4*)&Ct[row][k0];
    float4 xb = *(const float4*)&Ct[row][k0 + 4];
    short8 H, L;
    H[0] = f2bf(xa.x); H[1] = f2bf(xa.y); H[2] = f2bf(xa.z); H[3] = f2bf(xa.w);
    H[4] = f2bf(xb.x); H[5] = f2bf(xb.y); H[6] = f2bf(xb.z); H[7] = f2bf(xb.w);
    L[0] = f2bf(xa.x - bf2f(H[0])); L[1] = f2bf(xa.y - bf2f(H[1]));
    L[2] = f2bf(xa.z - bf2f(H[2])); L[3] = f2bf(xa.w - bf2f(H[3]));
    L[4] = f2bf(xb.x - bf2f(H[4])); L[5] = f2bf(xb.y - bf2f(H[5]));
    L[6] = f2bf(xb.z - bf2f(H[6])); L[7] = f2bf(xb.w - bf2f(H[7]));
    size_t u = ((size_t)((r16b + r16o) * 8 + fk) * 2) * 512 + (size_t)fl * 8;
    *(short8*)(Af + u) = H;
    *(short8*)(Af + u + 512) = L;
    *(short8*)(hg + (size_t)(rb + row) * DD + k0) = H;
  }
}

// ---------------------------------------------------------------- decode (reads bf16 hg)
__global__ __launch_bounds__(256) void kDec(const short* __restrict__ hg,
                                            const int* __restrict__ aidx,
                                            const float* __restrict__ W4,
                                            const float* __restrict__ W5,
                                            float* __restrict__ Q) {
  __shared__ float tmp[4];
  int b = blockIdx.x, j = threadIdx.x;
  float s = blockSum256(bf2f(hg[(size_t)(NN + b) * DD + j]) * W4[j], tmp);
  int a = aidx[b];
  float za = bf2f(hg[(size_t)a * DD + j]);
  float q = blockSum256(fmaxf(za * s, 0.f) * W5[j], tmp);
  if (j == 0) Q[b] = q;
}

// ---------------------------------------------------------------- launcher
extern "C" void kernel_launch(void* const* d_in, const int* in_sizes, int n_in,
                              void* d_out, int out_size, void* d_ws, size_t ws_size,
                              hipStream_t stream) {
  (void)in_sizes; (void)n_in; (void)out_size; (void)ws_size;
  const int*   edge_src = (const int*)d_in[0];
  const int*   edge_dst = (const int*)d_in[1];
  const float* edge_w   = (const float*)d_in[2];
  const int*   bassign  = (const int*)d_in[3];
  const int*   aidx     = (const int*)d_in[4];
  const float* Xf       = (const float*)d_in[5];
  const float* Xs       = (const float*)d_in[6];
  const float* W1       = (const float*)d_in[7];
  const float* W2       = (const float*)d_in[8];
  const float* W3       = (const float*)d_in[9];
  const float* linW     = (const float*)d_in[10];
  const float* linB     = (const float*)d_in[11];
  const float* W4       = (const float*)d_in[12];
  const float* W5       = (const float*)d_in[13];
  float* Q = (float*)d_out;

  char* base = (char*)d_ws;
  const size_t NB = (size_t)NT * DD * 4;   // 20.5 MB (split-fragment plane-pair bytes)
  short* hg   = (short*)(base);            // NB/2: bf16 h, in-place across depths
  short* Af   = (short*)(base + NB / 2);   // NB: split A-fragments, in-place
  short* Avf  = (short*)(base + NB / 2 + NB);  // NB: split hnv-fragments
  size_t o = NB / 2 + 2 * NB;
  short* Bf   = (short*)(base + o); o += (size_t)DD * 512 * 2 * 2;  // 512 KB, fragment order
  long long* sedge = (long long*)(base + o); o += (size_t)EE * 8;
  int*   snode= (int*)(base + o);   o += (size_t)NN * 4;
  int*   rank = (int*)(base + o);   o += (size_t)EE * 4;
  int*   rankB= (int*)(base + o);   o += (size_t)NN * 4;
  int*   offn = (int*)(base + o);   o += (size_t)(NN + 4) * 4;
  int*   offb = (int*)(base + o);   o += (size_t)(BB + 4) * 4;
  int*   curn8= (int*)(base + o);   o += (size_t)8 * NN * 4;
  int*   curn = (int*)(base + o);   o += (size_t)NN * 4;
  int*   pre8 = (int*)(base + o);   o += (size_t)8 * NN * 4;
  int*   bhist= (int*)(base + o);   o += (size_t)NBB * 64 * 4;
  int*   gpre = (int*)(base + o);   o += (size_t)NBB * 64 * 4;
  int*   curb = (int*)(base + o);   o += (size_t)BB * 4;

  hipMemsetAsync(curn8, 0, (size_t)8 * NN * 4, stream);

  kPre<<<NCB + 64 + NT / 16, 256, 0, stream>>>(Xf, Xs, W1, hg, Af,
                                               edge_dst, bassign, curn8, bhist,
                                               rank, rankB,
                                               W2, W3, linW, Bf);
  kAux<<<NBB + 64, 256, 0, stream>>>(curn8, curn, pre8, bhist, gpre, curb);
  kScan<<<1, 1024, 0, stream>>>(curn, offn, curb, offb);
  kPlace<<<(EE + 255) / 256, 256, 0, stream>>>(edge_src, edge_dst, edge_w, bassign,
                                               offn, pre8, offb, gpre, rank, rankB,
                                               sedge, snode);
  for (int d = 0; d < DEPTH; d++) {
    kAgg<<<4 * (NT / 8), 512, 0, stream>>>(hg, offn, sedge, offb, snode, Avf);
    kUpdM<<<NT / TRU, 512, 0, stream>>>(Af, Avf, Bf, linB, hg);
  }
  kDec<<<BB, 256, 0, stream>>>(hg, aidx, W4, W5, Q);
}

// Round 11
// 313.859 us; speedup vs baseline: 1.0497x; 1.0497x over previous
//
#include <hip/hip_runtime.h>

#define NN 20000
#define EE 320000
#define BB 64
#define DD 256
#define DEPTH 3
#define NT (NN + BB)   // h rows + hs rows appended (NT = 20064 = 16*1254 = 48*418 = 8*2508)

typedef __attribute__((ext_vector_type(8))) short short8;
typedef __attribute__((ext_vector_type(4))) float floatx4;

// ---------------------------------------------------------------- bf16 split helpers
__device__ __forceinline__ short f2bf(float x) {
  union { float f; unsigned u; } v; v.f = x;
  unsigned r = v.u + 0x7fffu + ((v.u >> 16) & 1u);  // RNE
  return (short)(r >> 16);
}
__device__ __forceinline__ float bf2f(short s) {
  union { unsigned u; float f; } v; v.u = ((unsigned)(unsigned short)s) << 16;
  return v.f;
}

// ---------------------------------------------------------------- fragment-order split store
// A-fragment layout: Af[(((row>>4)*8 + kc)*2 + plane)*512 + (kg*16 + (row&15))*8 + kel]
__device__ __forceinline__ void storeFragRow8(short* __restrict__ P, int row, int c0,
                                              const float* a) {
  short8 H, L;
  #pragma unroll
  for (int k = 0; k < 8; k++) {
    short hh = f2bf(a[k]);
    H[k] = hh;
    L[k] = f2bf(a[k] - bf2f(hh));
  }
  int kc = c0 >> 5, kg = (c0 >> 3) & 3;
  size_t u = ((size_t)((row >> 4) * 8 + kc) * 2) * 512 + (size_t)(kg * 16 + (row & 15)) * 8;
  *(short8*)(P + u) = H;
  *(short8*)(P + u + 512) = L;
}

// ---------------------------------------------------------------- reductions
__device__ __forceinline__ float blockSum256(float v, float* tmp) {
  #pragma unroll
  for (int o = 32; o > 0; o >>= 1) v += __shfl_down(v, o, 64);
  if ((threadIdx.x & 63) == 0) tmp[threadIdx.x >> 6] = v;
  __syncthreads();
  float r = tmp[0] + tmp[1] + tmp[2] + tmp[3];
  __syncthreads();
  return r;
}

// ---------------------------------------------------------------- kPre: rank atomics + kM + encode
// DECLARED AT FLOOR after 5 null structural experiments (r2/r5/r6/r9/r10); best
// remaining hypothesis: kPre absorbs the harness's 268MB re-poison L2-cold +
// writeback drain (fill = 44us at 76% HBM immediately before) -- not fixable
// from inside the kernel. Counters: VALU 6%, HBM 12%, occ 23%, no pipe busy.
#define NCB ((EE + 255) / 256)   // 1250
#define NBB ((NN + 255) / 256)   // 79 (blocks that contain nodes)
__global__ __launch_bounds__(256) void kPre(const float* __restrict__ X,
                                            const float* __restrict__ Xs,
                                            const float* __restrict__ W1,
                                            short* __restrict__ hg,
                                            short* __restrict__ Af,
                                            const int* __restrict__ dst,
                                            const int* __restrict__ bassign,
                                            int* curn8,
                                            int* __restrict__ bhist,
                                            int* __restrict__ rank,
                                            int* __restrict__ rankB,
                                            const float* __restrict__ W2,
                                            const float* __restrict__ W3,
                                            const float* __restrict__ linW,
                                            short* __restrict__ Bf) {
  __shared__ int hc[64];
  __shared__ __align__(16) short Hs[16][264];   // 264: stride 132 dwords %32 = 4 -> <=2-way
  __shared__ __align__(16) short Ls[16][264];
  float (*Wl)[DD] = (float(*)[DD])&Hs[0][0];    // M-phase overlay: 8KB <= Hs' 8.4KB
  int bid = blockIdx.x, j = threadIdx.x;
  if (bid < NCB) {
    if (j < 64) hc[j] = 0;
    __syncthreads();
    int t = bid * 256 + j;
    if (t < NN) rankB[t] = atomicAdd(&hc[bassign[t]], 1);     // LDS-only local rank
    if (t < EE) rank[t] = atomicAdd(&curn8[(bid & 7) * NN + dst[t]], 1);
    __syncthreads();
    if (bid < NBB && j < 64) bhist[bid * 64 + j] = hc[j];     // coalesced, non-atomic
  } else if (bid < NCB + 64) {
    // ---- M' rows rbase..rbase+7 (M2 = W2 @ linW_top for rows<256, else M3)
    int rbase = (bid - NCB) * 8;                 // 0..504
    bool second = rbase >= 256;
    const float* W = second ? W3 : W2;
    const float* L = linW + (second ? DD * DD : 0);
    int i0 = second ? (rbase - 256) : rbase;
    for (int q = j; q < 8 * DD; q += 256) Wl[q >> 8][q & 255] = W[(size_t)(i0 + (q >> 8)) * DD + (q & 255)];
    __syncthreads();
    float acc[8];
    #pragma unroll
    for (int r = 0; r < 8; r++) acc[r] = 0.f;
    #pragma unroll 4
    for (int k = 0; k < DD; k++) {
      float lv = L[(size_t)k * DD + j];
      #pragma unroll
      for (int r = 0; r < 8; r++) acc[r] = fmaf(Wl[r][k], lv, acc[r]);
    }
    #pragma unroll
    for (int r = 0; r < 8; r++) {
      int kk = rbase + r;                        // row index in B' (0..511)
      short hi = f2bf(acc[r]);
      short lo = f2bf(acc[r] - bf2f(hi));
      int kc = kk >> 5, kg = (kk >> 3) & 3, kel = kk & 7;
      int n16 = j >> 4, m16 = j & 15;
      size_t idx = ((size_t)(kc * 16 + n16) * 2) * 512 + (kg * 16 + m16) * 8 + kel;
      Bf[idx] = hi;
      Bf[idx + 512] = lo;
    }
  } else {
    // ---- encode: 16 rows per block, 16 threads/row x 16 cols/thread
    int rg = bid - NCB - 64;         // row-group 0..1253
    int rl = j >> 4;                 // row-in-group 0..15 (16 lanes each, shfl<16 safe)
    int ci = j & 15;
    int r = rg * 16 + rl;
    int c0 = ci * 16;
    const float* x = (r < NN) ? (X + (size_t)r * 2) : (Xs + (size_t)(r - NN) * 2);
    float x0 = x[0], x1 = x[1];
    float v[16];
    float ss = 0.f;
    #pragma unroll
    for (int q = 0; q < 4; q++) {
      float4 wa = *(const float4*)(W1 + c0 + q * 4);
      float4 wb = *(const float4*)(W1 + DD + c0 + q * 4);
      float a0 = fmaxf(fmaf(x0, wa.x, x1 * wb.x), 0.f);
      float a1 = fmaxf(fmaf(x0, wa.y, x1 * wb.y), 0.f);
      float a2 = fmaxf(fmaf(x0, wa.z, x1 * wb.z), 0.f);
      float a3 = fmaxf(fmaf(x0, wa.w, x1 * wb.w), 0.f);
      v[q * 4 + 0] = a0; v[q * 4 + 1] = a1; v[q * 4 + 2] = a2; v[q * 4 + 3] = a3;
      ss = fmaf(a0, a0, ss); ss = fmaf(a1, a1, ss);
      ss = fmaf(a2, a2, ss); ss = fmaf(a3, a3, ss);
    }
    #pragma unroll
    for (int o = 1; o < 16; o <<= 1) ss += __shfl_xor(ss, o, 64);
    float inv = 1.f / fmaxf(sqrtf(ss), 1e-12f);
    short8 H0, H1, L0, L1;
    #pragma unroll
    for (int k = 0; k < 8; k++) {
      float s0 = v[k] * inv;
      float s1 = v[8 + k] * inv;
      short h0 = f2bf(s0), h1 = f2bf(s1);
      H0[k] = h0; H1[k] = h1;
      L0[k] = f2bf(s0 - bf2f(h0)); L1[k] = f2bf(s1 - bf2f(h1));
    }
    *(short8*)(hg + (size_t)r * DD + c0)     = H0;
    *(short8*)(hg + (size_t)r * DD + c0 + 8) = H1;
    *(short8*)&Hs[rl][c0] = H0;  *(short8*)&Hs[rl][c0 + 8] = H1;
    *(short8*)&Ls[rl][c0] = L0;  *(short8*)&Ls[rl][c0 + 8] = L1;
    __syncthreads();
    // ---- coalesced fragment write: thread j covers fragment kc=j>>5, positions j&31, +32
    int kc = j >> 5, p0 = j & 31;
    #pragma unroll
    for (int half = 0; half < 2; half++) {
      int p = p0 + half * 32;
      int prow = p & 15, kg = p >> 4;
      size_t ub = ((size_t)(rg * 8 + kc) * 2) * 512 + (size_t)p * 8;
      *(short8*)(Af + ub)       = *(const short8*)&Hs[prow][kc * 32 + kg * 8];
      *(short8*)(Af + ub + 512) = *(const short8*)&Ls[prow][kc * 32 + kg * 8];
    }
  }
}

// ---------------------------------------------------------------- kAux: sum8 + local scans
// round-28: node blocks additionally emit a BLOCK-LOCAL exclusive scan (lexcl) +
// blkSum, so the serial 1024-thread kScan (20-barrier ladder over 80KB, ~10us)
// shrinks to kScan2's two tiny wave-scans. Slot arithmetic stays IDENTICAL to
// r10 (same offn/offb values) -> absmax must stay exactly 6.103516e-05.
__global__ __launch_bounds__(256) void kAux(const int* __restrict__ curn8,
                                            int* __restrict__ lexcl,
                                            int* __restrict__ blkSum,
                                            int* __restrict__ pre8,
                                            const int* __restrict__ bhist,
                                            int* __restrict__ gpre,
                                            int* __restrict__ curb) {
  int bid = blockIdx.x;
  if (bid < NBB) {
    __shared__ int sc[256];
    int tid = threadIdx.x;
    int n = bid * 256 + tid;
    int tot = 0;
    if (n < NN) {
      int run = 0;
      #pragma unroll
      for (int c = 0; c < 8; c++) {
        pre8[c * NN + n] = run;
        run += curn8[c * NN + n];
      }
      tot = run;
    }
    sc[tid] = tot;
    __syncthreads();
    for (int o = 1; o < 256; o <<= 1) {
      int x = (tid >= o) ? sc[tid - o] : 0;
      __syncthreads();
      sc[tid] += x;
      __syncthreads();
    }
    if (n < NN) lexcl[n] = sc[tid] - tot;
    if (tid == 255) blkSum[bid] = sc[255];
  } else {
    int b = bid - NBB;               // batch 0..63
    int lane = threadIdx.x;
    if (lane < 64) {
      int run = 0;
      for (int base = 0; base < NBB; base += 64) {
        int idx = base + lane;
        int v = (idx < NBB) ? bhist[idx * 64 + b] : 0;
        int incl = v;
        #pragma unroll
        for (int o = 1; o < 64; o <<= 1) {
          int x = __shfl_up(incl, o, 64);
          if (lane >= o) incl += x;
        }
        if (idx < NBB) gpre[idx * 64 + b] = run + (incl - v);
        run += __shfl(incl, 63, 64);
      }
      if (lane == 0) curb[b] = run;
    }
  }
}

// ---------------------------------------------------------------- kScan2: tiny top-level scans
// round-28: replaces the 1024-thread serial kScan. Wave-scans blkSum[79] -> blkBase
// and curb[64] -> offb. offn materialized later by kPlace (offn[NN] = EE const).
__global__ __launch_bounds__(64) void kScan2(const int* __restrict__ blkSum,
                                             int* __restrict__ blkBase,
                                             const int* __restrict__ curb,
                                             int* __restrict__ offb) {
  int lane = threadIdx.x;
  int run = 0;
  for (int base = 0; base < NBB; base += 64) {
    int idx = base + lane;
    int v = (idx < NBB) ? blkSum[idx] : 0;
    int incl = v;
    #pragma unroll
    for (int o = 1; o < 64; o <<= 1) {
      int x = __shfl_up(incl, o, 64);
      if (lane >= o) incl += x;
    }
    if (idx < NBB) blkBase[idx] = run + (incl - v);
    run += __shfl(incl, 63, 64);
  }
  int v = curb[lane];
  int incl = v;
  #pragma unroll
  for (int o = 1; o < 64; o <<= 1) {
    int x = __shfl_up(incl, o, 64);
    if (lane >= o) incl += x;
  }
  offb[lane] = incl - v;
  if (lane == 63) offb[BB] = incl;
}

// ---------------------------------------------------------------- kPlace: rank -> position, no atomics
// round-28: offn computed inline (blkBase + lexcl) and materialized for kAgg.
__global__ __launch_bounds__(256) void kPlace(const int* __restrict__ src,
                                              const int* __restrict__ dst,
                                              const float* __restrict__ w,
                                              const int* __restrict__ bassign,
                                              const int* __restrict__ blkBase,
                                              const int* __restrict__ lexcl,
                                              int* __restrict__ offn,
                                              const int* __restrict__ pre8,
                                              const int* __restrict__ offb,
                                              const int* __restrict__ gpre,
                                              const int* __restrict__ rank,
                                              const int* __restrict__ rankB,
                                              long long* sedge, int* snode) {
  int t = blockIdx.x * 256 + threadIdx.x;
  if (t < EE) {
    unsigned long long e = (unsigned long long)(unsigned)src[t]
                         | ((unsigned long long)(unsigned)__float_as_int(w[t]) << 32);
    int c = (t >> 8) & 7;                      // kPre rank-block id & 7
    int d = dst[t];
    sedge[blkBase[d >> 8] + lexcl[d] + pre8[c * NN + d] + rank[t]] = (long long)e;
  }
  if (t < NN) {
    int b = bassign[t];
    offn[t] = blkBase[t >> 8] + lexcl[t];
    snode[offb[b] + gpre[(t >> 8) * 64 + b] + rankB[t]] = t;
  }
  if (t == 0) offn[NN] = EE;
}

// ---------------------------------------------------------------- aggregation (free-running waves)
// ONE FREE-RUNNING WAVE per (node, slice), zero LDS, zero __syncthreads.
// Declared at line-service floor (3 structures converge at ~38-43us).
__global__ __launch_bounds__(512) void kAgg(const short* __restrict__ hg,
                                            const int* __restrict__ offn,
                                            const long long* __restrict__ sedge,
                                            const int* __restrict__ offb,
                                            const int* __restrict__ snode,
                                            short* __restrict__ Avf) {
  int bid = blockIdx.x;
  int slice = bid & 3, group = bid >> 2;      // group 0..2507
  int t = threadIdx.x;
  int w = t >> 6, lane = t & 63;
  int eg = lane >> 3;          // edge group 0..7
  int pc = lane & 7;           // 16B piece 0..7
  int colB = slice * 64 + pc * 8;             // 8 bf16 cols per lane
  float acc[8];
  #pragma unroll
  for (int jj = 0; jj < 8; jj++) acc[jj] = 0.f;

  if (group < 8) {
    // ---- batch rows: row b0+w per wave, snode index list (weight 1)
    int row = group * 8 + w;                  // 0..63
    int s = offb[row], e = offb[row + 1];
    for (int i = s; i < e; i += 16) {
      int i0 = i + eg, i1 = i + 8 + eg;
      int n0 = snode[min(i0, e - 1)];
      int n1 = snode[min(i1, e - 1)];
      float w0 = (i0 < e) ? 1.f : 0.f;
      float w1 = (i1 < e) ? 1.f : 0.f;
      short8 a0 = *(const short8*)(hg + (size_t)n0 * DD + colB);
      short8 a1 = *(const short8*)(hg + (size_t)n1 * DD + colB);
      #pragma unroll
      for (int jj = 0; jj < 8; jj++)
        acc[jj] = fmaf(w1, bf2f(a1[jj]), fmaf(w0, bf2f(a0[jj]), acc[jj]));
    }
    #pragma unroll
    for (int o = 8; o < 64; o <<= 1)
      #pragma unroll
      for (int jj = 0; jj < 8; jj++) acc[jj] += __shfl_xor(acc[jj], o, 64);
    if (eg == 0) storeFragRow8(Avf, NN + row, colB, acc);
  } else {
    // ---- edge nodes: node first+w per wave, sedge packed (src | w<<32)
    int node = (group - 8) * 8 + w;
    int s = offn[node], e = offn[node + 1];
    for (int i = s; i < e; i += 16) {
      int i0 = i + eg, i1 = i + 8 + eg;
      long long e0v = sedge[min(i0, e - 1)];
      long long e1v = sedge[min(i1, e - 1)];
      float w0 = (i0 < e) ? __int_as_float((int)(e0v >> 32)) : 0.f;
      float w1 = (i1 < e) ? __int_as_float((int)(e1v >> 32)) : 0.f;
      unsigned r0 = (unsigned)(e0v & 0xffffffffLL);
      unsigned r1 = (unsigned)(e1v & 0xffffffffLL);
      short8 a0 = *(const short8*)(hg + (size_t)r0 * DD + colB);
      short8 a1 = *(const short8*)(hg + (size_t)r1 * DD + colB);
      #pragma unroll
      for (int jj = 0; jj < 8; jj++)
        acc[jj] = fmaf(w1, bf2f(a1[jj]), fmaf(w0, bf2f(a0[jj]), acc[jj]));
    }
    #pragma unroll
    for (int o = 8; o < 64; o <<= 1)
      #pragma unroll
      for (int jj = 0; jj < 8; jj++) acc[jj] += __shfl_xor(acc[jj], o, 64);
    if (eg == 0) storeFragRow8(Avf, node, colB, acc);
  }
}

// ---------------------------------------------------------------- MFMA dual-GEMM + fused l2norm
// TRU=48 (r5 best). DMA double-buffered per-wave staging, barrier-free main loop.
#define TRU 48
__global__ __launch_bounds__(512) void kUpdM(short* __restrict__ Af,
                                             const short* __restrict__ Avf,
                                             const short* __restrict__ Bf,
                                             const float* __restrict__ lb,
                                             short* __restrict__ hg) {
  __shared__ __align__(16) short Bst[8][2][4][512];   // [wave][buf][ct*2+plane][512] = 64KB
  __shared__ float ssq[8][TRU];
  float (*Ct)[260] = (float(*)[260]) & Bst[0][0][0][0];   // epilogue overlay (49.9KB)
  const int t = threadIdx.x;
  const int rb = blockIdx.x * TRU;
  const int wid = t >> 6;          // 0..7
  const int lane = t & 63;
  const int wc = wid * 32;         // wave col offset (8 waves cover 256 cols)
  const int m16 = lane & 15;
  const int kg = lane >> 4;        // 0..3
  const int r16b = blockIdx.x * 3; // first 16-row group

  floatx4 acc[3][2];
  #pragma unroll
  for (int ct = 0; ct < 2; ct++) {
    float b = lb[wc + ct * 16 + m16];
    #pragma unroll
    for (int rt = 0; rt < 3; rt++) acc[rt][ct] = (floatx4){b, b, b, b};
  }

  short8 aH[2][3], aL[2][3];       // [kc&1][rt] -- static indices after full unroll

  // prologue: stage kc=0, load A(0)
  #pragma unroll
  for (int f = 0; f < 4; f++) {
    const short* g = Bf + ((size_t)((0 * 16 + wid * 2) * 2 + f)) * 512 + lane * 8;
    __builtin_amdgcn_global_load_lds((const __attribute__((address_space(1))) unsigned int*)g,
                                     (__attribute__((address_space(3))) unsigned int*)&Bst[wid][0][f][0],
                                     16, 0, 0);
  }
  #pragma unroll
  for (int rt = 0; rt < 3; rt++) {
    const short* ap = Af + ((size_t)((r16b + rt) * 8 + 0) * 2) * 512 + lane * 8;
    aH[0][rt] = *(const short8*)ap;
    aL[0][rt] = *(const short8*)(ap + 512);
  }

  #pragma unroll
  for (int kc = 0; kc < 16; kc++) {
    const int buf = kc & 1;
    if (kc < 15) {
      #pragma unroll
      for (int f = 0; f < 4; f++) {
        const short* g = Bf + ((size_t)(((kc + 1) * 16 + wid * 2) * 2 + f)) * 512 + lane * 8;
        __builtin_amdgcn_global_load_lds((const __attribute__((address_space(1))) unsigned int*)g,
                                         (__attribute__((address_space(3))) unsigned int*)&Bst[wid][buf ^ 1][f][0],
                                         16, 0, 0);
      }
      asm volatile("s_waitcnt vmcnt(4)" ::: "memory");
    } else {
      asm volatile("s_waitcnt vmcnt(0)" ::: "memory");
    }
    __builtin_amdgcn_sched_barrier(0);
    if (kc < 15) {
      const short* Ab = ((kc + 1) < 8) ? Af : Avf;
      const int kcl = (kc + 1) & 7;
      #pragma unroll
      for (int rt = 0; rt < 3; rt++) {
        const short* ap = Ab + ((size_t)((r16b + rt) * 8 + kcl) * 2) * 512 + lane * 8;
        aH[(kc + 1) & 1][rt] = *(const short8*)ap;
        aL[(kc + 1) & 1][rt] = *(const short8*)(ap + 512);
      }
    }
    #pragma unroll
    for (int ct = 0; ct < 2; ct++) {
      short8 bh = *(const short8*)&Bst[wid][buf][ct * 2 + 0][lane * 8];
      short8 bl = *(const short8*)&Bst[wid][buf][ct * 2 + 1][lane * 8];
      #pragma unroll
      for (int rt = 0; rt < 3; rt++) {
        acc[rt][ct] = __builtin_amdgcn_mfma_f32_16x16x32_bf16(aH[buf][rt], bh, acc[rt][ct], 0, 0, 0);
        acc[rt][ct] = __builtin_amdgcn_mfma_f32_16x16x32_bf16(aH[buf][rt], bl, acc[rt][ct], 0, 0, 0);
        acc[rt][ct] = __builtin_amdgcn_mfma_f32_16x16x32_bf16(aL[buf][rt], bh, acc[rt][ct], 0, 0, 0);
      }
    }
  }

  // ---- epilogue: relu + row l2norm (C/D: col=lane&15, row=(lane>>4)*4+reg)
  float p[3][4];
  #pragma unroll
  for (int rt = 0; rt < 3; rt++)
    #pragma unroll
    for (int reg = 0; reg < 4; reg++) {
      float s = 0.f;
      #pragma unroll
      for (int ct = 0; ct < 2; ct++) {
        float x = fmaxf(acc[rt][ct][reg], 0.f);
        s = fmaf(x, x, s);
      }
      p[rt][reg] = s;
    }
  #pragma unroll
  for (int o = 1; o < 16; o <<= 1)
    #pragma unroll
    for (int rt = 0; rt < 3; rt++)
      #pragma unroll
      for (int reg = 0; reg < 4; reg++)
        p[rt][reg] += __shfl_xor(p[rt][reg], o, 64);
  if (m16 == 0) {
    #pragma unroll
    for (int rt = 0; rt < 3; rt++)
      #pragma unroll
      for (int reg = 0; reg < 4; reg++)
        ssq[wid][rt * 16 + kg * 4 + reg] = p[rt][reg];
  }
  __syncthreads();   // after this barrier all waves are past their last Bst read
  #pragma unroll
  for (int rt = 0; rt < 3; rt++) {
    #pragma unroll
    for (int reg = 0; reg < 4; reg++) {
      int row = rt * 16 + kg * 4 + reg;
      float ss = 0.f;
      #pragma unroll
      for (int ww = 0; ww < 8; ww++) ss += ssq[ww][row];
      float inv = 1.f / fmaxf(sqrtf(ss), 1e-12f);
      #pragma unroll
      for (int ct = 0; ct < 2; ct++) {
        int col = wc + ct * 16 + m16;
        Ct[row][col] = fmaxf(acc[rt][ct][reg], 0.f) * inv;
      }
    }
  }
  __syncthreads();
  // ---- fragment-order split write-back (in-place Af) + bf16 hg, 16B stores
  const int fl = lane;                 // lane-in-fragment
  const int fk = wid;                  // kc 0..7
  #pragma unroll
  for (int r16o = 0; r16o < 3; ++r16o) {
    int row = r16o * 16 + (fl & 15);
    int k0 = fk * 32 + (fl >> 4) * 8;
    float4 xa = *(const float4*)&Ct[row][k0];
    float4 xb = *(const float4*)&Ct[row][k0 + 4];
    short8 H, L;
    H[0] = f2bf(xa.x); H[1] = f2bf(xa.y); H[2] = f2bf(xa.z); H[3] = f2bf(xa.w);
    H[4] = f2bf(xb.x); H[5] = f2bf(xb.y); H[6] = f2bf(xb.z); H[7] = f2bf(xb.w);
    L[0] = f2bf(xa.x - bf2f(H[0])); L[1] = f2bf(xa.y - bf2f(H[1]));
    L[2] = f2bf(xa.z - bf2f(H[2])); L[3] = f2bf(xa.w - bf2f(H[3]));
    L[4] = f2bf(xb.x - bf2f(H[4])); L[5] = f2bf(xb.y - bf2f(H[5]));
    L[6] = f2bf(xb.z - bf2f(H[6])); L[7] = f2bf(xb.w - bf2f(H[7]));
    size_t u = ((size_t)((r16b + r16o) * 8 + fk) * 2) * 512 + (size_t)fl * 8;
    *(short8*)(Af + u) = H;
    *(short8*)(Af + u + 512) = L;
    *(short8*)(hg + (size_t)(rb + row) * DD + k0) = H;
  }
}

// ---------------------------------------------------------------- decode (reads bf16 hg)
__global__ __launch_bounds__(256) void kDec(const short* __restrict__ hg,
                                            const int* __restrict__ aidx,
                                            const float* __restrict__ W4,
                                            const float* __restrict__ W5,
                                            float* __restrict__ Q) {
  __shared__ float tmp[4];
  int b = blockIdx.x, j = threadIdx.x;
  float s = blockSum256(bf2f(hg[(size_t)(NN + b) * DD + j]) * W4[j], tmp);
  int a = aidx[b];
  float za = bf2f(hg[(size_t)a * DD + j]);
  float q = blockSum256(fmaxf(za * s, 0.f) * W5[j], tmp);
  if (j == 0) Q[b] = q;
}

// ---------------------------------------------------------------- launcher
extern "C" void kernel_launch(void* const* d_in, const int* in_sizes, int n_in,
                              void* d_out, int out_size, void* d_ws, size_t ws_size,
                              hipStream_t stream) {
  (void)in_sizes; (void)n_in; (void)out_size; (void)ws_size;
  const int*   edge_src = (const int*)d_in[0];
  const int*   edge_dst = (const int*)d_in[1];
  const float* edge_w   = (const float*)d_in[2];
  const int*   bassign  = (const int*)d_in[3];
  const int*   aidx     = (const int*)d_in[4];
  const float* Xf       = (const float*)d_in[5];
  const float* Xs       = (const float*)d_in[6];
  const float* W1       = (const float*)d_in[7];
  const float* W2       = (const float*)d_in[8];
  const float* W3       = (const float*)d_in[9];
  const float* linW     = (const float*)d_in[10];
  const float* linB     = (const float*)d_in[11];
  const float* W4       = (const float*)d_in[12];
  const float* W5       = (const float*)d_in[13];
  float* Q = (float*)d_out;

  char* base = (char*)d_ws;
  const size_t NB = (size_t)NT * DD * 4;   // 20.5 MB (split-fragment plane-pair bytes)
  short* hg   = (short*)(base);            // NB/2: bf16 h, in-place across depths
  short* Af   = (short*)(base + NB / 2);   // NB: split A-fragments, in-place
  short* Avf  = (short*)(base + NB / 2 + NB);  // NB: split hnv-fragments
  size_t o = NB / 2 + 2 * NB;
  short* Bf   = (short*)(base + o); o += (size_t)DD * 512 * 2 * 2;  // 512 KB, fragment order
  long long* sedge = (long long*)(base + o); o += (size_t)EE * 8;
  int*   snode= (int*)(base + o);   o += (size_t)NN * 4;
  int*   rank = (int*)(base + o);   o += (size_t)EE * 4;
  int*   rankB= (int*)(base + o);   o += (size_t)NN * 4;
  int*   offn = (int*)(base + o);   o += (size_t)(NN + 4) * 4;
  int*   offb = (int*)(base + o);   o += (size_t)(BB + 4) * 4;
  int*   curn8= (int*)(base + o);   o += (size_t)8 * NN * 4;
  int*   pre8 = (int*)(base + o);   o += (size_t)8 * NN * 4;
  int*   lexcl= (int*)(base + o);   o += (size_t)NN * 4;
  int*   blkSum=(int*)(base + o);   o += (size_t)(NBB + 4) * 4;
  int*   blkBase=(int*)(base + o);  o += (size_t)(NBB + 4) * 4;
  int*   bhist= (int*)(base + o);   o += (size_t)NBB * 64 * 4;
  int*   gpre = (int*)(base + o);   o += (size_t)NBB * 64 * 4;
  int*   curb = (int*)(base + o);   o += (size_t)BB * 4;

  hipMemsetAsync(curn8, 0, (size_t)8 * NN * 4, stream);

  kPre<<<NCB + 64 + NT / 16, 256, 0, stream>>>(Xf, Xs, W1, hg, Af,
                                               edge_dst, bassign, curn8, bhist,
                                               rank, rankB,
                                               W2, W3, linW, Bf);
  kAux<<<NBB + 64, 256, 0, stream>>>(curn8, lexcl, blkSum, pre8, bhist, gpre, curb);
  kScan2<<<1, 64, 0, stream>>>(blkSum, blkBase, curb, offb);
  kPlace<<<(EE + 255) / 256, 256, 0, stream>>>(edge_src, edge_dst, edge_w, bassign,
                                               blkBase, lexcl, offn, pre8, offb, gpre,
                                               rank, rankB, sedge, snode);
  for (int d = 0; d < DEPTH; d++) {
    kAgg<<<4 * (NT / 8), 512, 0, stream>>>(hg, offn, sedge, offb, snode, Avf);
    kUpdM<<<NT / TRU, 512, 0, stream>>>(Af, Avf, Bf, linB, hg);
  }
  kDec<<<BB, 256, 0, stream>>>(hg, aidx, W4, W5, Q);
}